// Round 6
// baseline (34.828 us; speedup 1.0000x reference)
//
#include <hip/hip_runtime.h>

#define IH 4096
#define IW 4096
#define OH 4094
#define OW 4094
#define CGROUPS 1024            // col-groups per row (1024*4 = 4096 >= 4094)
#define NWG 16376               // (1024*4094)/256 exactly
#define XCD_CHUNK 2047          // NWG / 8

__global__ __launch_bounds__(256) void conv3x3_kernel(
    const float* __restrict__ in, const float* __restrict__ wgt,
    const float* __restrict__ bias, float* __restrict__ out) {

    // XCD-aware bijective swizzle: NWG % 8 == 0, so simple chunked remap.
    int b   = blockIdx.x;
    int swz = (b & 7) * XCD_CHUNK + (b >> 3);
    int idx = swz * 256 + (int)threadIdx.x;

    int cg  = idx & (CGROUPS - 1);
    int row = idx >> 10;               // output row
    if (row >= OH) return;             // exact grid; never taken, keeps it safe
    int x = cg << 2;                   // output col start (multiple of 4)

    // Weights + bias: wave-uniform loads, served from cache.
    float wv[9];
    #pragma unroll
    for (int i = 0; i < 9; ++i) wv[i] = wgt[i];
    float bs = bias[0];

    float acc0 = bs, acc1 = bs, acc2 = bs, acc3 = bs;

    #pragma unroll
    for (int kh = 0; kh < 3; ++kh) {
        const float* rp = in + (size_t)(row + kh) * IW + x;
        float4 a = *reinterpret_cast<const float4*>(rp);   // 16B-aligned
        float e4 = 0.f, e5 = 0.f;
        if (x + 5 < IW) {                                   // false only at x==4092
            float2 t = *reinterpret_cast<const float2*>(rp + 4);
            e4 = t.x; e5 = t.y;
        }
        float w0 = wv[kh * 3 + 0], w1 = wv[kh * 3 + 1], w2 = wv[kh * 3 + 2];
        acc0 += w0 * a.x + w1 * a.y + w2 * a.z;
        acc1 += w0 * a.y + w1 * a.z + w2 * a.w;
        acc2 += w0 * a.z + w1 * a.w + w2 * e4;
        acc3 += w0 * a.w + w1 * e4  + w2 * e5;
    }

    float* op = out + (size_t)row * OW + x;
    if (x + 4 <= OW) {                 // full 4-wide store (x <= 4088)
        op[0] = acc0; op[1] = acc1; op[2] = acc2; op[3] = acc3;
    } else {                           // x == 4092: only cols 4092, 4093 exist
        op[0] = acc0; op[1] = acc1;
    }
}

extern "C" void kernel_launch(void* const* d_in, const int* in_sizes, int n_in,
                              void* d_out, int out_size, void* d_ws, size_t ws_size,
                              hipStream_t stream) {
    const float* in   = (const float*)d_in[0];
    const float* wgt  = (const float*)d_in[1];
    const float* bias = (const float*)d_in[2];
    float* out        = (float*)d_out;

    conv3x3_kernel<<<NWG, 256, 0, stream>>>(in, wgt, bias, out);
}

// Round 7
// 31.739 us; speedup vs baseline: 1.0973x; 1.0973x over previous
//
#include <hip/hip_runtime.h>

#define IW 4096
#define IH 4096
#define OH 4094
#define OW 4094
#define CG 1024              // col-groups per row (4 cols each)
#define RG 1024              // row-groups (4 rows each; last group has 2)
#define NWG 4096             // (1024 * 1024) / 256
#define XCHUNK 512           // NWG / 8

__global__ __launch_bounds__(256) void conv3x3_r4(
    const float* __restrict__ in, const float* __restrict__ wgt,
    const float* __restrict__ bias, float* __restrict__ out) {

    // XCD-aware bijective swizzle (4096 % 8 == 0).
    int b   = blockIdx.x;
    int swz = (b & 7) * XCHUNK + (b >> 3);
    int idx = swz * 256 + (int)threadIdx.x;

    int cg   = idx & (CG - 1);
    int rg   = idx >> 10;          // all 256 threads of a block share rg
    int x    = cg << 2;            // output col start (multiple of 4)
    int row0 = rg << 2;            // output row start

    float wv[9];
#pragma unroll
    for (int i = 0; i < 9; ++i) wv[i] = wgt[i];
    float bs = bias[0];

    int nr    = (row0 + 4 <= OH) ? 4 : (OH - row0);  // 4, or 2 at rg==1023 (uniform)
    int nload = nr + 2;                              // input rows needed

    // 6 input row-segments of 6 floats each; 12 load instrs, all independent.
    float r[6][6];
#pragma unroll
    for (int t = 0; t < 6; ++t) {
        if (t < nload) {
            const float* rp = in + (size_t)(row0 + t) * IW + x;
            float4 a = *reinterpret_cast<const float4*>(rp);   // 16B-aligned
            r[t][0] = a.x; r[t][1] = a.y; r[t][2] = a.z; r[t][3] = a.w;
            if (x + 5 < IW) {                                  // false only at x==4092
                float2 e = *reinterpret_cast<const float2*>(rp + 4);
                r[t][4] = e.x; r[t][5] = e.y;
            } else { r[t][4] = 0.f; r[t][5] = 0.f; }
        } else {
#pragma unroll
            for (int j = 0; j < 6; ++j) r[t][j] = 0.f;
        }
    }

    float acc[4][4];
#pragma unroll
    for (int i = 0; i < 4; ++i)
#pragma unroll
        for (int c = 0; c < 4; ++c) acc[i][c] = bs;

    // 144 FMAs: output row `orow` uses input rows orow..orow+2.
#pragma unroll
    for (int orow = 0; orow < 4; ++orow) {
#pragma unroll
        for (int kh = 0; kh < 3; ++kh) {
            int t = orow + kh;
            float w0 = wv[kh * 3 + 0], w1 = wv[kh * 3 + 1], w2 = wv[kh * 3 + 2];
#pragma unroll
            for (int c = 0; c < 4; ++c)
                acc[orow][c] += w0 * r[t][c] + w1 * r[t][c + 1] + w2 * r[t][c + 2];
        }
    }

    int nc = (x + 4 <= OW) ? 4 : (OW - x);           // 4, or 2 at x==4092
#pragma unroll
    for (int orow = 0; orow < 4; ++orow) {
        if (orow < nr) {
            float* op = out + (size_t)(row0 + orow) * OW + x;
            if (nc == 4) {
                op[0] = acc[orow][0]; op[1] = acc[orow][1];
                op[2] = acc[orow][2]; op[3] = acc[orow][3];
            } else {
                op[0] = acc[orow][0]; op[1] = acc[orow][1];
            }
        }
    }
}

extern "C" void kernel_launch(void* const* d_in, const int* in_sizes, int n_in,
                              void* d_out, int out_size, void* d_ws, size_t ws_size,
                              hipStream_t stream) {
    const float* in   = (const float*)d_in[0];
    const float* wgt  = (const float*)d_in[1];
    const float* bias = (const float*)d_in[2];
    float* out        = (float*)d_out;

    conv3x3_r4<<<NWG, 256, 0, stream>>>(in, wgt, bias, out);
}

// Round 9
// 27.771 us; speedup vs baseline: 1.2541x; 1.1429x over previous
//
#include <hip/hip_runtime.h>

#define IW 4096
#define IH 4096
#define OH 4094
#define OW 4094
#define CG 1024              // col-groups per row (4 cols each)
#define NWG 4096             // (1024 * 1024) / 256
#define XCHUNK 512           // NWG / 8

typedef float f32x4 __attribute__((ext_vector_type(4)));
typedef float f32x2 __attribute__((ext_vector_type(2)));

__global__ __launch_bounds__(256) void conv3x3_r4v(
    const float* __restrict__ in, const float* __restrict__ wgt,
    const float* __restrict__ bias, float* __restrict__ out) {

    // XCD-aware bijective swizzle (4096 % 8 == 0).
    int b   = blockIdx.x;
    int swz = (b & 7) * XCHUNK + (b >> 3);
    int idx = swz * 256 + (int)threadIdx.x;

    int cg   = idx & (CG - 1);
    int rg   = idx >> 10;          // all 256 threads of a block share rg
    int x    = cg << 2;            // output col start (multiple of 4)
    int row0 = rg << 2;            // output row start (even)

    float wv[9];
#pragma unroll
    for (int i = 0; i < 9; ++i) wv[i] = wgt[i];
    float bs = bias[0];

    int nr    = (row0 + 4 <= OH) ? 4 : (OH - row0);  // 4, or 2 at rg==1023 (uniform)
    int nload = nr + 2;                              // input rows needed

    // 6 input row-segments of 6 floats each; independent loads back-to-back.
    float r[6][6];
#pragma unroll
    for (int t = 0; t < 6; ++t) {
        if (t < nload) {
            const float* rp = in + (size_t)(row0 + t) * IW + x;
            float4 a = *reinterpret_cast<const float4*>(rp);   // 16B-aligned
            r[t][0] = a.x; r[t][1] = a.y; r[t][2] = a.z; r[t][3] = a.w;
            if (x + 5 < IW) {                                  // false only at x==4092
                float2 e = *reinterpret_cast<const float2*>(rp + 4);
                r[t][4] = e.x; r[t][5] = e.y;
            } else { r[t][4] = 0.f; r[t][5] = 0.f; }
        } else {
#pragma unroll
            for (int j = 0; j < 6; ++j) r[t][j] = 0.f;
        }
    }

    float acc[4][4];
#pragma unroll
    for (int i = 0; i < 4; ++i)
#pragma unroll
        for (int c = 0; c < 4; ++c) acc[i][c] = bs;

#pragma unroll
    for (int orow = 0; orow < 4; ++orow) {
#pragma unroll
        for (int kh = 0; kh < 3; ++kh) {
            int t = orow + kh;
            float w0 = wv[kh * 3 + 0], w1 = wv[kh * 3 + 1], w2 = wv[kh * 3 + 2];
#pragma unroll
            for (int c = 0; c < 4; ++c)
                acc[orow][c] += w0 * r[t][c] + w1 * r[t][c + 1] + w2 * r[t][c + 2];
        }
    }

    // Stores: row0 is even, so orow even -> byte offset % 16 == 0 (float4 OK),
    // orow odd -> % 16 == 8 (two float2). Nontemporal: output is never re-read.
    int nc = (x + 4 <= OW) ? 4 : (OW - x);           // 4, or 2 at x==4092
#pragma unroll
    for (int orow = 0; orow < 4; ++orow) {
        if (orow < nr) {
            float* op = out + (size_t)(row0 + orow) * OW + x;
            if (nc == 4) {
                if ((orow & 1) == 0) {
                    f32x4 v = { acc[orow][0], acc[orow][1],
                                acc[orow][2], acc[orow][3] };
                    __builtin_nontemporal_store(v, reinterpret_cast<f32x4*>(op));
                } else {
                    f32x2 v0 = { acc[orow][0], acc[orow][1] };
                    f32x2 v1 = { acc[orow][2], acc[orow][3] };
                    __builtin_nontemporal_store(v0, reinterpret_cast<f32x2*>(op));
                    __builtin_nontemporal_store(v1, reinterpret_cast<f32x2*>(op + 2));
                }
            } else {
                f32x2 v0 = { acc[orow][0], acc[orow][1] };
                __builtin_nontemporal_store(v0, reinterpret_cast<f32x2*>(op));
            }
        }
    }
}

extern "C" void kernel_launch(void* const* d_in, const int* in_sizes, int n_in,
                              void* d_out, int out_size, void* d_ws, size_t ws_size,
                              hipStream_t stream) {
    const float* in   = (const float*)d_in[0];
    const float* wgt  = (const float*)d_in[1];
    const float* bias = (const float*)d_in[2];
    float* out        = (float*)d_out;

    conv3x3_r4v<<<NWG, 256, 0, stream>>>(in, wgt, bias, out);
}